// Round 1
// baseline (514.354 us; speedup 1.0000x reference)
//
#include <hip/hip_runtime.h>

#define HID 512
#define POOL 4096
#define N_OBJ 1280
#define N_REL 16384
#define NOC 151
#define NRC 51

typedef _Float16 half_t;
typedef half_t h16x8 __attribute__((ext_vector_type(8)));
typedef float f32x4 __attribute__((ext_vector_type(4)));

// LDS tile stride: 64 + 8 halves = 144 B -> 4-bank rotation per row, 2-way max (free)
#define LDSTR 72

// ---------------------------------------------------------------------------
// K1: E(1280x1024) = edge_ctx(1280x512) @ We(512x1024) + be   (f16 out to ws)
// 64x64 tile, 4 waves, each wave: 16 rows x 64 cols, mfma 16x16x32 f16
// ---------------------------------------------------------------------------
__global__ __launch_bounds__(256) void k1_edge_rep(
    const float* __restrict__ edge_ctx,
    const float* __restrict__ We,
    const float* __restrict__ be,
    half_t* __restrict__ E)
{
    __shared__ __align__(16) half_t As[64 * LDSTR];
    __shared__ __align__(16) half_t Bs[64 * LDSTR];  // transposed: Bs[n][kk]

    const int m0 = blockIdx.x * 64;
    const int n0 = blockIdx.y * 64;
    const int t = threadIdx.x;
    const int wave = t >> 6, lane = t & 63;
    const int quad = lane >> 4, l16 = lane & 15;

    const int ar  = t >> 2;         // A staging: row in tile
    const int akb = (t & 3) * 16;   // A staging: k base
    const int bn  = (t & 15) * 4;   // B staging: n base (4 wide)
    const int bk  = t >> 4;         // B staging: kk (+16*it)

    f32x4 acc[4] = {};

    for (int k0 = 0; k0 < HID; k0 += 64) {
        // stage A (fp32 -> f16)
        {
            const float* src = edge_ctx + (m0 + ar) * HID + k0 + akb;
#pragma unroll
            for (int i = 0; i < 2; ++i) {
                float4 va = *(const float4*)(src + 8 * i);
                float4 vb = *(const float4*)(src + 8 * i + 4);
                h16x8 o;
                o[0] = (half_t)va.x; o[1] = (half_t)va.y;
                o[2] = (half_t)va.z; o[3] = (half_t)va.w;
                o[4] = (half_t)vb.x; o[5] = (half_t)vb.y;
                o[6] = (half_t)vb.z; o[7] = (half_t)vb.w;
                *(h16x8*)&As[ar * LDSTR + akb + 8 * i] = o;
            }
        }
        // stage B transposed (fp32 -> f16): Bs[n][kk] = We[k0+kk][n0+n]
#pragma unroll
        for (int it = 0; it < 4; ++it) {
            int kk = bk + 16 * it;
            float4 v = *(const float4*)(We + (size_t)(k0 + kk) * 1024 + n0 + bn);
            Bs[(bn + 0) * LDSTR + kk] = (half_t)v.x;
            Bs[(bn + 1) * LDSTR + kk] = (half_t)v.y;
            Bs[(bn + 2) * LDSTR + kk] = (half_t)v.z;
            Bs[(bn + 3) * LDSTR + kk] = (half_t)v.w;
        }
        __syncthreads();
#pragma unroll
        for (int s = 0; s < 2; ++s) {
            h16x8 a = *(const h16x8*)&As[(wave * 16 + l16) * LDSTR + s * 32 + quad * 8];
#pragma unroll
            for (int nt = 0; nt < 4; ++nt) {
                h16x8 b = *(const h16x8*)&Bs[(nt * 16 + l16) * LDSTR + s * 32 + quad * 8];
                acc[nt] = __builtin_amdgcn_mfma_f32_16x16x32_f16(a, b, acc[nt], 0, 0, 0);
            }
        }
        __syncthreads();
    }
    // epilogue: + bias, store f16
#pragma unroll
    for (int nt = 0; nt < 4; ++nt) {
        int n = n0 + nt * 16 + l16;
        float bias = be[n];
#pragma unroll
        for (int r = 0; r < 4; ++r) {
            int m = m0 + wave * 16 + quad * 4 + r;
            E[(size_t)m * 1024 + n] = (half_t)(acc[nt][r] + bias);
        }
    }
}

// ---------------------------------------------------------------------------
// K2: z=0: H = E[:, :512] @ Wc[:512,:] + b_cat ; z=1: T = E[:,512:] @ Wc[512:,:]
// M=1280, N=4096, K=512 per z. Same tile structure as K1. A is already f16.
// ---------------------------------------------------------------------------
__global__ __launch_bounds__(256) void k2_ht(
    const half_t* __restrict__ E,
    const float* __restrict__ Wc,
    const float* __restrict__ bcat,
    half_t* __restrict__ Hws,
    half_t* __restrict__ Tws)
{
    __shared__ __align__(16) half_t As[64 * LDSTR];
    __shared__ __align__(16) half_t Bs[64 * LDSTR];

    const int z  = blockIdx.z;
    const int m0 = blockIdx.x * 64;
    const int n0 = blockIdx.y * 64;
    const int t = threadIdx.x;
    const int wave = t >> 6, lane = t & 63;
    const int quad = lane >> 4, l16 = lane & 15;

    const int ar  = t >> 2;
    const int akb = (t & 3) * 16;
    const int bn  = (t & 15) * 4;
    const int bk  = t >> 4;

    f32x4 acc[4] = {};

    for (int k0 = 0; k0 < HID; k0 += 64) {
        // stage A: direct f16 copy from E
        {
            const half_t* src = E + (size_t)(m0 + ar) * 1024 + z * 512 + k0 + akb;
            *(h16x8*)&As[ar * LDSTR + akb]     = *(const h16x8*)(src);
            *(h16x8*)&As[ar * LDSTR + akb + 8] = *(const h16x8*)(src + 8);
        }
        // stage B transposed: Bs[n][kk] = Wc[z*512+k0+kk][n0+n]
#pragma unroll
        for (int it = 0; it < 4; ++it) {
            int kk = bk + 16 * it;
            float4 v = *(const float4*)(Wc + (size_t)(z * 512 + k0 + kk) * POOL + n0 + bn);
            Bs[(bn + 0) * LDSTR + kk] = (half_t)v.x;
            Bs[(bn + 1) * LDSTR + kk] = (half_t)v.y;
            Bs[(bn + 2) * LDSTR + kk] = (half_t)v.z;
            Bs[(bn + 3) * LDSTR + kk] = (half_t)v.w;
        }
        __syncthreads();
#pragma unroll
        for (int s = 0; s < 2; ++s) {
            h16x8 a = *(const h16x8*)&As[(wave * 16 + l16) * LDSTR + s * 32 + quad * 8];
#pragma unroll
            for (int nt = 0; nt < 4; ++nt) {
                h16x8 b = *(const h16x8*)&Bs[(nt * 16 + l16) * LDSTR + s * 32 + quad * 8];
                acc[nt] = __builtin_amdgcn_mfma_f32_16x16x32_f16(a, b, acc[nt], 0, 0, 0);
            }
        }
        __syncthreads();
    }
    half_t* outp = z ? Tws : Hws;
#pragma unroll
    for (int nt = 0; nt < 4; ++nt) {
        int n = n0 + nt * 16 + l16;
        float bias = z ? 0.0f : bcat[n];
#pragma unroll
        for (int r = 0; r < 4; ++r) {
            int m = m0 + wave * 16 + quad * 4 + r;
            outp[(size_t)m * POOL + n] = (half_t)(acc[nt][r] + bias);
        }
    }
}

// ---------------------------------------------------------------------------
// K2b: Wt[n][k] = f16(W_rel[k][n]), n in [0,64) zero-padded past 51
// ---------------------------------------------------------------------------
__global__ __launch_bounds__(256) void k2b_wt(
    const float* __restrict__ Wrel, half_t* __restrict__ Wt)
{
    int k = blockIdx.x * 256 + threadIdx.x;  // 0..4095
#pragma unroll 8
    for (int n = 0; n < 64; ++n) {
        float v = (n < NRC) ? Wrel[(size_t)k * NRC + n] : 0.0f;
        Wt[(size_t)n * POOL + k] = (half_t)v;
    }
}

// ---------------------------------------------------------------------------
// K3: fused  out[r] = ((H[i_r]+T[j_r]) .* u[r]) @ W_rel + b_rel + freq[bias_idx]
// 64 rows/block, K-loop over 4096 in chunks of 64, f16 MFMA, N=64 (51 real)
// ---------------------------------------------------------------------------
__global__ __launch_bounds__(256) void k3_main(
    const float* __restrict__ unionf,
    const half_t* __restrict__ Hws,
    const half_t* __restrict__ Tws,
    const half_t* __restrict__ Wt,
    const float* __restrict__ brel,
    const float* __restrict__ freq,
    const int* __restrict__ pair_idx,
    const int* __restrict__ obj_preds,
    float* __restrict__ out)
{
    __shared__ __align__(16) half_t As[64 * LDSTR];
    __shared__ __align__(16) half_t Bs[64 * LDSTR];

    const int R0 = blockIdx.x * 64;
    const int t = threadIdx.x;
    const int wave = t >> 6, lane = t & 63;
    const int quad = lane >> 4, l16 = lane & 15;

    const int ar  = t >> 2;         // rel-row in tile for A staging
    const int akb = (t & 3) * 16;   // k base within chunk

    const int2 pr = *(const int2*)(pair_idx + 2 * (R0 + ar));
    const half_t* Hrow = Hws + (size_t)pr.x * POOL;
    const half_t* Trow = Tws + (size_t)pr.y * POOL;
    const float*  urow = unionf + (size_t)(R0 + ar) * POOL;

    f32x4 acc[4] = {};

    for (int k0 = 0; k0 < POOL; k0 += 64) {
        // stage A: f16( (H[i]+T[j]) * u )
#pragma unroll
        for (int i = 0; i < 2; ++i) {
            h16x8 hv = *(const h16x8*)(Hrow + k0 + akb + 8 * i);
            h16x8 tv = *(const h16x8*)(Trow + k0 + akb + 8 * i);
            float4 ua = *(const float4*)(urow + k0 + akb + 8 * i);
            float4 ub = *(const float4*)(urow + k0 + akb + 8 * i + 4);
            h16x8 o;
            o[0] = (half_t)(((float)hv[0] + (float)tv[0]) * ua.x);
            o[1] = (half_t)(((float)hv[1] + (float)tv[1]) * ua.y);
            o[2] = (half_t)(((float)hv[2] + (float)tv[2]) * ua.z);
            o[3] = (half_t)(((float)hv[3] + (float)tv[3]) * ua.w);
            o[4] = (half_t)(((float)hv[4] + (float)tv[4]) * ub.x);
            o[5] = (half_t)(((float)hv[5] + (float)tv[5]) * ub.y);
            o[6] = (half_t)(((float)hv[6] + (float)tv[6]) * ub.z);
            o[7] = (half_t)(((float)hv[7] + (float)tv[7]) * ub.w);
            *(h16x8*)&As[ar * LDSTR + akb + 8 * i] = o;
        }
        // stage B: Bs[n][kk] = Wt[n][k0+kk]  (already f16, already transposed)
        {
            const half_t* src = Wt + (size_t)ar * POOL + k0 + akb;  // reuse ar as n
            *(h16x8*)&Bs[ar * LDSTR + akb]     = *(const h16x8*)(src);
            *(h16x8*)&Bs[ar * LDSTR + akb + 8] = *(const h16x8*)(src + 8);
        }
        __syncthreads();
#pragma unroll
        for (int s = 0; s < 2; ++s) {
            h16x8 a = *(const h16x8*)&As[(wave * 16 + l16) * LDSTR + s * 32 + quad * 8];
#pragma unroll
            for (int nt = 0; nt < 4; ++nt) {
                h16x8 b = *(const h16x8*)&Bs[(nt * 16 + l16) * LDSTR + s * 32 + quad * 8];
                acc[nt] = __builtin_amdgcn_mfma_f32_16x16x32_f16(a, b, acc[nt], 0, 0, 0);
            }
        }
        __syncthreads();
    }
    // epilogue: + b_rel + freq_table[obj_preds[i]*151 + obj_preds[j]]
#pragma unroll
    for (int r = 0; r < 4; ++r) {
        int grow = R0 + wave * 16 + quad * 4 + r;
        int2 p = *(const int2*)(pair_idx + 2 * grow);
        int fidx = obj_preds[p.x] * NOC + obj_preds[p.y];
        const float* frow = freq + (size_t)fidx * NRC;
#pragma unroll
        for (int nt = 0; nt < 4; ++nt) {
            int n = nt * 16 + l16;
            if (n < NRC)
                out[(size_t)grow * NRC + n] = acc[nt][r] + brel[n] + frow[n];
        }
    }
}

// ---------------------------------------------------------------------------
extern "C" void kernel_launch(void* const* d_in, const int* in_sizes, int n_in,
                              void* d_out, int out_size, void* d_ws, size_t ws_size,
                              hipStream_t stream) {
    const float* edge_ctx  = (const float*)d_in[0];
    const float* unionf    = (const float*)d_in[1];
    const float* We        = (const float*)d_in[2];
    const float* be        = (const float*)d_in[3];
    const float* Wc        = (const float*)d_in[4];
    const float* bcat      = (const float*)d_in[5];
    const float* Wrel      = (const float*)d_in[6];
    const float* brel      = (const float*)d_in[7];
    const float* freq      = (const float*)d_in[8];
    const int*   pair_idx  = (const int*)d_in[9];
    const int*   obj_preds = (const int*)d_in[10];
    float* out = (float*)d_out;

    char* ws = (char*)d_ws;
    // ws layout (all 16B-aligned):
    //   E : 1280*1024 f16 = 2,621,440 B   @ 0
    //   H : 1280*4096 f16 = 10,485,760 B  @ 2,621,440
    //   T : 1280*4096 f16 = 10,485,760 B  @ 13,107,200
    //   Wt:   64*4096 f16 =    524,288 B  @ 23,592,960   (total ~24.1 MB)
    half_t* E  = (half_t*)(ws);
    half_t* H  = (half_t*)(ws + 2621440);
    half_t* T  = (half_t*)(ws + 13107200);
    half_t* Wt = (half_t*)(ws + 23592960);

    k1_edge_rep<<<dim3(N_OBJ / 64, 1024 / 64), 256, 0, stream>>>(edge_ctx, We, be, E);
    k2b_wt<<<POOL / 256, 256, 0, stream>>>(Wrel, Wt);
    k2_ht<<<dim3(N_OBJ / 64, POOL / 64, 2), 256, 0, stream>>>(E, Wc, bcat, H, T);
    k3_main<<<N_REL / 64, 256, 0, stream>>>(unionf, H, T, Wt, brel, freq,
                                            pair_idx, obj_preds, out);
}

// Round 2
// 478.524 us; speedup vs baseline: 1.0749x; 1.0749x over previous
//
#include <hip/hip_runtime.h>

#define HID 512
#define POOL 4096
#define N_OBJ 1280
#define N_REL 16384
#define NOC 151
#define NRC 51
#define KSPLIT 4

typedef _Float16 half_t;
typedef half_t h16x8 __attribute__((ext_vector_type(8)));
typedef float f32x4 __attribute__((ext_vector_type(4)));

// LDS tile stride: 64 + 8 halves = 144 B -> 4-bank rotation per row, 2-way max (free)
#define LDSTR 72

// ---------------------------------------------------------------------------
// KT: generic transpose+downconvert. src: K x N fp32 (n-fast) -> dst: N x K f16
// (k-fast). 64x64 tile per block, 256 threads.
// ---------------------------------------------------------------------------
__global__ __launch_bounds__(256) void kt_transpose(
    const float* __restrict__ src, half_t* __restrict__ dst, int K, int N)
{
    __shared__ __align__(16) half_t Ts[64 * LDSTR];  // [n][k], padded
    const int kb = blockIdx.x * 64, nb = blockIdx.y * 64;
    const int t = threadIdx.x;
    const int kr = t >> 4;          // 0..15
    const int nc = (t & 15) * 4;    // 0..60
#pragma unroll
    for (int p = 0; p < 4; ++p) {
        float4 v = *(const float4*)(src + (size_t)(kb + kr + 16 * p) * N + nb + nc);
        Ts[(nc + 0) * LDSTR + kr + 16 * p] = (half_t)v.x;
        Ts[(nc + 1) * LDSTR + kr + 16 * p] = (half_t)v.y;
        Ts[(nc + 2) * LDSTR + kr + 16 * p] = (half_t)v.z;
        Ts[(nc + 3) * LDSTR + kr + 16 * p] = (half_t)v.w;
    }
    __syncthreads();
    const int n = t >> 2, kk = (t & 3) * 16;
    half_t* d = dst + (size_t)(nb + n) * K + kb + kk;
    *(h16x8*)(d)     = *(const h16x8*)&Ts[n * LDSTR + kk];
    *(h16x8*)(d + 8) = *(const h16x8*)&Ts[n * LDSTR + kk + 8];
}

// ---------------------------------------------------------------------------
// K1: E(1280x1024) = edge_ctx(1280x512) @ We(512x1024) + be   (f16 out to ws)
// B from pre-transposed Wet (1024 x 512 f16).
// ---------------------------------------------------------------------------
__global__ __launch_bounds__(256) void k1_edge_rep(
    const float* __restrict__ edge_ctx,
    const half_t* __restrict__ Wet,
    const float* __restrict__ be,
    half_t* __restrict__ E)
{
    __shared__ __align__(16) half_t As[64 * LDSTR];
    __shared__ __align__(16) half_t Bs[64 * LDSTR];

    const int m0 = blockIdx.x * 64;
    const int n0 = blockIdx.y * 64;
    const int t = threadIdx.x;
    const int wave = t >> 6, lane = t & 63;
    const int quad = lane >> 4, l16 = lane & 15;

    const int ar  = t >> 2;         // staging row in tile
    const int akb = (t & 3) * 16;   // staging k base

    f32x4 acc[4] = {};

    for (int k0 = 0; k0 < HID; k0 += 64) {
        // stage A (fp32 -> f16)
        {
            const float* src = edge_ctx + (size_t)(m0 + ar) * HID + k0 + akb;
#pragma unroll
            for (int i = 0; i < 2; ++i) {
                float4 va = *(const float4*)(src + 8 * i);
                float4 vb = *(const float4*)(src + 8 * i + 4);
                h16x8 o;
                o[0] = (half_t)va.x; o[1] = (half_t)va.y;
                o[2] = (half_t)va.z; o[3] = (half_t)va.w;
                o[4] = (half_t)vb.x; o[5] = (half_t)vb.y;
                o[6] = (half_t)vb.z; o[7] = (half_t)vb.w;
                *(h16x8*)&As[ar * LDSTR + akb + 8 * i] = o;
            }
        }
        // stage B: vector copy from Wet[n][k]
        {
            const half_t* src = Wet + (size_t)(n0 + ar) * HID + k0 + akb;
            *(h16x8*)&Bs[ar * LDSTR + akb]     = *(const h16x8*)(src);
            *(h16x8*)&Bs[ar * LDSTR + akb + 8] = *(const h16x8*)(src + 8);
        }
        __syncthreads();
#pragma unroll
        for (int s = 0; s < 2; ++s) {
            h16x8 a = *(const h16x8*)&As[(wave * 16 + l16) * LDSTR + s * 32 + quad * 8];
#pragma unroll
            for (int nt = 0; nt < 4; ++nt) {
                h16x8 b = *(const h16x8*)&Bs[(nt * 16 + l16) * LDSTR + s * 32 + quad * 8];
                acc[nt] = __builtin_amdgcn_mfma_f32_16x16x32_f16(a, b, acc[nt], 0, 0, 0);
            }
        }
        __syncthreads();
    }
#pragma unroll
    for (int nt = 0; nt < 4; ++nt) {
        int n = n0 + nt * 16 + l16;
        float bias = be[n];
#pragma unroll
        for (int r = 0; r < 4; ++r) {
            int m = m0 + wave * 16 + quad * 4 + r;
            E[(size_t)m * 1024 + n] = (half_t)(acc[nt][r] + bias);
        }
    }
}

// ---------------------------------------------------------------------------
// K2: z=0: H = E[:, :512] @ Wc[:512,:] + b_cat ; z=1: T = E[:,512:] @ Wc[512:,:]
// B from pre-transposed Wct (4096 x 1024 f16, k-fast).
// ---------------------------------------------------------------------------
__global__ __launch_bounds__(256) void k2_ht(
    const half_t* __restrict__ E,
    const half_t* __restrict__ Wct,
    const float* __restrict__ bcat,
    half_t* __restrict__ Hws,
    half_t* __restrict__ Tws)
{
    __shared__ __align__(16) half_t As[64 * LDSTR];
    __shared__ __align__(16) half_t Bs[64 * LDSTR];

    const int z  = blockIdx.z;
    const int m0 = blockIdx.x * 64;
    const int n0 = blockIdx.y * 64;
    const int t = threadIdx.x;
    const int wave = t >> 6, lane = t & 63;
    const int quad = lane >> 4, l16 = lane & 15;

    const int ar  = t >> 2;
    const int akb = (t & 3) * 16;

    f32x4 acc[4] = {};

    for (int k0 = 0; k0 < HID; k0 += 64) {
        {
            const half_t* src = E + (size_t)(m0 + ar) * 1024 + z * 512 + k0 + akb;
            *(h16x8*)&As[ar * LDSTR + akb]     = *(const h16x8*)(src);
            *(h16x8*)&As[ar * LDSTR + akb + 8] = *(const h16x8*)(src + 8);
        }
        {
            const half_t* src = Wct + (size_t)(n0 + ar) * 1024 + z * 512 + k0 + akb;
            *(h16x8*)&Bs[ar * LDSTR + akb]     = *(const h16x8*)(src);
            *(h16x8*)&Bs[ar * LDSTR + akb + 8] = *(const h16x8*)(src + 8);
        }
        __syncthreads();
#pragma unroll
        for (int s = 0; s < 2; ++s) {
            h16x8 a = *(const h16x8*)&As[(wave * 16 + l16) * LDSTR + s * 32 + quad * 8];
#pragma unroll
            for (int nt = 0; nt < 4; ++nt) {
                h16x8 b = *(const h16x8*)&Bs[(nt * 16 + l16) * LDSTR + s * 32 + quad * 8];
                acc[nt] = __builtin_amdgcn_mfma_f32_16x16x32_f16(a, b, acc[nt], 0, 0, 0);
            }
        }
        __syncthreads();
    }
    half_t* outp = z ? Tws : Hws;
#pragma unroll
    for (int nt = 0; nt < 4; ++nt) {
        int n = n0 + nt * 16 + l16;
        float bias = z ? 0.0f : bcat[n];
#pragma unroll
        for (int r = 0; r < 4; ++r) {
            int m = m0 + wave * 16 + quad * 4 + r;
            outp[(size_t)m * POOL + n] = (half_t)(acc[nt][r] + bias);
        }
    }
}

// ---------------------------------------------------------------------------
// K2b: Wt[n][k] = f16(W_rel[k][n]), n in [0,64) zero-padded past 51
// ---------------------------------------------------------------------------
__global__ __launch_bounds__(256) void k2b_wt(
    const float* __restrict__ Wrel, half_t* __restrict__ Wt)
{
    int k = blockIdx.x * 256 + threadIdx.x;  // 0..4095
#pragma unroll 8
    for (int n = 0; n < 64; ++n) {
        float v = (n < NRC) ? Wrel[(size_t)k * NRC + n] : 0.0f;
        Wt[(size_t)n * POOL + k] = (half_t)v;
    }
}

// ---------------------------------------------------------------------------
// K3: fused  out[r] = ((H[i_r]+T[j_r]) .* u[r]) @ W_rel + b_rel + freq[bias_idx]
// 64 rows/block, K-split x4 (1024 per block), atomicAdd into zeroed out.
// ---------------------------------------------------------------------------
__global__ __launch_bounds__(256) void k3_main(
    const float* __restrict__ unionf,
    const half_t* __restrict__ Hws,
    const half_t* __restrict__ Tws,
    const half_t* __restrict__ Wt,
    const float* __restrict__ brel,
    const float* __restrict__ freq,
    const int* __restrict__ pair_idx,
    const int* __restrict__ obj_preds,
    float* __restrict__ out)
{
    __shared__ __align__(16) half_t As[64 * LDSTR];
    __shared__ __align__(16) half_t Bs[64 * LDSTR];

    const int R0 = blockIdx.x * 64;
    const int kbase = blockIdx.y * (POOL / KSPLIT);
    const int t = threadIdx.x;
    const int wave = t >> 6, lane = t & 63;
    const int quad = lane >> 4, l16 = lane & 15;

    const int ar  = t >> 2;
    const int akb = (t & 3) * 16;

    const int2 pr = *(const int2*)(pair_idx + 2 * (R0 + ar));
    const half_t* Hrow = Hws + (size_t)pr.x * POOL;
    const half_t* Trow = Tws + (size_t)pr.y * POOL;
    const float*  urow = unionf + (size_t)(R0 + ar) * POOL;

    f32x4 acc[4] = {};

    for (int k0 = kbase; k0 < kbase + POOL / KSPLIT; k0 += 64) {
        // stage A: f16( (H[i]+T[j]) * u )
#pragma unroll
        for (int i = 0; i < 2; ++i) {
            h16x8 hv = *(const h16x8*)(Hrow + k0 + akb + 8 * i);
            h16x8 tv = *(const h16x8*)(Trow + k0 + akb + 8 * i);
            float4 ua = *(const float4*)(urow + k0 + akb + 8 * i);
            float4 ub = *(const float4*)(urow + k0 + akb + 8 * i + 4);
            h16x8 o;
            o[0] = (half_t)(((float)hv[0] + (float)tv[0]) * ua.x);
            o[1] = (half_t)(((float)hv[1] + (float)tv[1]) * ua.y);
            o[2] = (half_t)(((float)hv[2] + (float)tv[2]) * ua.z);
            o[3] = (half_t)(((float)hv[3] + (float)tv[3]) * ua.w);
            o[4] = (half_t)(((float)hv[4] + (float)tv[4]) * ub.x);
            o[5] = (half_t)(((float)hv[5] + (float)tv[5]) * ub.y);
            o[6] = (half_t)(((float)hv[6] + (float)tv[6]) * ub.z);
            o[7] = (half_t)(((float)hv[7] + (float)tv[7]) * ub.w);
            *(h16x8*)&As[ar * LDSTR + akb + 8 * i] = o;
        }
        // stage B: Bs[n][kk] = Wt[n][k0+kk]
        {
            const half_t* src = Wt + (size_t)ar * POOL + k0 + akb;  // ar as n
            *(h16x8*)&Bs[ar * LDSTR + akb]     = *(const h16x8*)(src);
            *(h16x8*)&Bs[ar * LDSTR + akb + 8] = *(const h16x8*)(src + 8);
        }
        __syncthreads();
#pragma unroll
        for (int s = 0; s < 2; ++s) {
            h16x8 a = *(const h16x8*)&As[(wave * 16 + l16) * LDSTR + s * 32 + quad * 8];
#pragma unroll
            for (int nt = 0; nt < 4; ++nt) {
                h16x8 b = *(const h16x8*)&Bs[(nt * 16 + l16) * LDSTR + s * 32 + quad * 8];
                acc[nt] = __builtin_amdgcn_mfma_f32_16x16x32_f16(a, b, acc[nt], 0, 0, 0);
            }
        }
        __syncthreads();
    }
    // epilogue: atomic accumulate; split 0 folds in b_rel + freq_table row
    const bool first = (blockIdx.y == 0);
#pragma unroll
    for (int r = 0; r < 4; ++r) {
        int grow = R0 + wave * 16 + quad * 4 + r;
        const float* frow = nullptr;
        if (first) {
            int2 p = *(const int2*)(pair_idx + 2 * grow);
            frow = freq + (size_t)(obj_preds[p.x] * NOC + obj_preds[p.y]) * NRC;
        }
#pragma unroll
        for (int nt = 0; nt < 4; ++nt) {
            int n = nt * 16 + l16;
            if (n < NRC) {
                float v = acc[nt][r];
                if (first) v += brel[n] + frow[n];
                atomicAdd(&out[(size_t)grow * NRC + n], v);
            }
        }
    }
}

// ---------------------------------------------------------------------------
extern "C" void kernel_launch(void* const* d_in, const int* in_sizes, int n_in,
                              void* d_out, int out_size, void* d_ws, size_t ws_size,
                              hipStream_t stream) {
    const float* edge_ctx  = (const float*)d_in[0];
    const float* unionf    = (const float*)d_in[1];
    const float* We        = (const float*)d_in[2];
    const float* be        = (const float*)d_in[3];
    const float* Wc        = (const float*)d_in[4];
    const float* bcat      = (const float*)d_in[5];
    const float* Wrel      = (const float*)d_in[6];
    const float* brel      = (const float*)d_in[7];
    const float* freq      = (const float*)d_in[8];
    const int*   pair_idx  = (const int*)d_in[9];
    const int*   obj_preds = (const int*)d_in[10];
    float* out = (float*)d_out;

    char* ws = (char*)d_ws;
    // ws layout (16B-aligned):
    //   E   : 1280*1024 f16 =  2,621,440 B  @ 0
    //   H   : 1280*4096 f16 = 10,485,760 B  @  2,621,440
    //   T   : 1280*4096 f16 = 10,485,760 B  @ 13,107,200
    //   Wt  :   64*4096 f16 =    524,288 B  @ 23,592,960
    //   Wct : 4096*1024 f16 =  8,388,608 B  @ 24,117,248
    //   Wet : 1024* 512 f16 =  1,048,576 B  @ 32,505,856   (total ~33.6 MB)
    half_t* E   = (half_t*)(ws);
    half_t* H   = (half_t*)(ws + 2621440);
    half_t* T   = (half_t*)(ws + 13107200);
    half_t* Wt  = (half_t*)(ws + 23592960);
    half_t* Wct = (half_t*)(ws + 24117248);
    half_t* Wet = (half_t*)(ws + 32505856);

    hipMemsetAsync(out, 0, (size_t)out_size * sizeof(float), stream);

    kt_transpose<<<dim3(HID / 64, 1024 / 64), 256, 0, stream>>>(We, Wet, HID, 1024);
    kt_transpose<<<dim3(1024 / 64, POOL / 64), 256, 0, stream>>>(Wc, Wct, 1024, POOL);
    k2b_wt<<<POOL / 256, 256, 0, stream>>>(Wrel, Wt);
    k1_edge_rep<<<dim3(N_OBJ / 64, 1024 / 64), 256, 0, stream>>>(edge_ctx, Wet, be, E);
    k2_ht<<<dim3(N_OBJ / 64, POOL / 64, 2), 256, 0, stream>>>(E, Wct, bcat, H, T);
    k3_main<<<dim3(N_REL / 64, KSPLIT), 256, 0, stream>>>(unionf, H, T, Wt, brel, freq,
                                                          pair_idx, obj_preds, out);
}

// Round 3
// 471.326 us; speedup vs baseline: 1.0913x; 1.0153x over previous
//
#include <hip/hip_runtime.h>

#define HID 512
#define POOL 4096
#define N_OBJ 1280
#define N_REL 16384
#define NOC 151
#define NRC 51
#define KSPLIT 4

typedef _Float16 half_t;
typedef half_t h16x8 __attribute__((ext_vector_type(8)));
typedef float f32x4 __attribute__((ext_vector_type(4)));

// LDS row stride for 64-k f16 tiles: 72 elems = 144 B. Both b128 reads and
// writes spread uniformly over the 8 four-bank groups (bandwidth-optimal).
#define LDSTR 72

// ---------------------------------------------------------------------------
// KT: generic transpose+downconvert. src: K x N fp32 (n-fast) -> dst: N x K f16
// ---------------------------------------------------------------------------
__global__ __launch_bounds__(256) void kt_transpose(
    const float* __restrict__ src, half_t* __restrict__ dst, int K, int N)
{
    __shared__ __align__(16) half_t Ts[64 * LDSTR];
    const int kb = blockIdx.x * 64, nb = blockIdx.y * 64;
    const int t = threadIdx.x;
    const int kr = t >> 4;
    const int nc = (t & 15) * 4;
#pragma unroll
    for (int p = 0; p < 4; ++p) {
        float4 v = *(const float4*)(src + (size_t)(kb + kr + 16 * p) * N + nb + nc);
        Ts[(nc + 0) * LDSTR + kr + 16 * p] = (half_t)v.x;
        Ts[(nc + 1) * LDSTR + kr + 16 * p] = (half_t)v.y;
        Ts[(nc + 2) * LDSTR + kr + 16 * p] = (half_t)v.z;
        Ts[(nc + 3) * LDSTR + kr + 16 * p] = (half_t)v.w;
    }
    __syncthreads();
    const int n = t >> 2, kk = (t & 3) * 16;
    half_t* d = dst + (size_t)(nb + n) * K + kb + kk;
    *(h16x8*)(d)     = *(const h16x8*)&Ts[n * LDSTR + kk];
    *(h16x8*)(d + 8) = *(const h16x8*)&Ts[n * LDSTR + kk + 8];
}

// ---------------------------------------------------------------------------
// K1: E(1280x1024) = edge_ctx(1280x512) @ We(512x1024) + be   (f16 out)
// 64x64 tile. B from pre-transposed Wet (1024x512 f16).
// ---------------------------------------------------------------------------
__global__ __launch_bounds__(256) void k1_edge_rep(
    const float* __restrict__ edge_ctx,
    const half_t* __restrict__ Wet,
    const float* __restrict__ be,
    half_t* __restrict__ E)
{
    __shared__ __align__(16) half_t As[64 * LDSTR];
    __shared__ __align__(16) half_t Bs[64 * LDSTR];

    const int m0 = blockIdx.x * 64;
    const int n0 = blockIdx.y * 64;
    const int t = threadIdx.x;
    const int wave = t >> 6, lane = t & 63;
    const int quad = lane >> 4, l16 = lane & 15;

    const int ar  = t >> 2;
    const int akb = (t & 3) * 16;

    f32x4 acc[4] = {};

    for (int k0 = 0; k0 < HID; k0 += 64) {
        {
            const float* src = edge_ctx + (size_t)(m0 + ar) * HID + k0 + akb;
#pragma unroll
            for (int i = 0; i < 2; ++i) {
                float4 va = *(const float4*)(src + 8 * i);
                float4 vb = *(const float4*)(src + 8 * i + 4);
                h16x8 o;
                o[0] = (half_t)va.x; o[1] = (half_t)va.y;
                o[2] = (half_t)va.z; o[3] = (half_t)va.w;
                o[4] = (half_t)vb.x; o[5] = (half_t)vb.y;
                o[6] = (half_t)vb.z; o[7] = (half_t)vb.w;
                *(h16x8*)&As[ar * LDSTR + akb + 8 * i] = o;
            }
        }
        {
            const half_t* src = Wet + (size_t)(n0 + ar) * HID + k0 + akb;
            *(h16x8*)&Bs[ar * LDSTR + akb]     = *(const h16x8*)(src);
            *(h16x8*)&Bs[ar * LDSTR + akb + 8] = *(const h16x8*)(src + 8);
        }
        __syncthreads();
#pragma unroll
        for (int s = 0; s < 2; ++s) {
            h16x8 a = *(const h16x8*)&As[(wave * 16 + l16) * LDSTR + s * 32 + quad * 8];
#pragma unroll
            for (int nt = 0; nt < 4; ++nt) {
                h16x8 b = *(const h16x8*)&Bs[(nt * 16 + l16) * LDSTR + s * 32 + quad * 8];
                acc[nt] = __builtin_amdgcn_mfma_f32_16x16x32_f16(a, b, acc[nt], 0, 0, 0);
            }
        }
        __syncthreads();
    }
#pragma unroll
    for (int nt = 0; nt < 4; ++nt) {
        int n = n0 + nt * 16 + l16;
        float bias = be[n];
#pragma unroll
        for (int r = 0; r < 4; ++r) {
            int m = m0 + wave * 16 + quad * 4 + r;
            E[(size_t)m * 1024 + n] = (half_t)(acc[nt][r] + bias);
        }
    }
}

// ---------------------------------------------------------------------------
// K2: 128x128 tile. z=0: H = E[:,:512]@Wc_top + b_cat ; z=1: T = E[:,512:]@Wc_bot
// 4 waves, each 64x64 quadrant = 4x4 frags, 32 MFMA + 16 ds_read_b128 per iter.
// ---------------------------------------------------------------------------
__global__ __launch_bounds__(256) void k2_ht(
    const half_t* __restrict__ E,
    const half_t* __restrict__ Wct,
    const float* __restrict__ bcat,
    half_t* __restrict__ Hws,
    half_t* __restrict__ Tws)
{
    __shared__ __align__(16) half_t As[128 * LDSTR];
    __shared__ __align__(16) half_t Bs[128 * LDSTR];

    const int z  = blockIdx.z;
    const int m0 = blockIdx.x * 128;
    const int n0 = blockIdx.y * 128;
    const int t = threadIdx.x;
    const int wave = t >> 6, lane = t & 63;
    const int quad = lane >> 4, l16 = lane & 15;
    const int wr = wave >> 1, wc = wave & 1;

    // staging: 8 lanes cover one 128B row-chunk; 4 passes of 32 rows
    const int srow = t >> 3;       // 0..31
    const int sc   = (t & 7) * 8;  // chunk offset in elems

    f32x4 acc[4][4] = {};

    for (int k0 = 0; k0 < HID; k0 += 64) {
#pragma unroll
        for (int p = 0; p < 4; ++p) {
            int row = srow + 32 * p;
            *(h16x8*)&As[row * LDSTR + sc] =
                *(const h16x8*)(E + (size_t)(m0 + row) * 1024 + z * 512 + k0 + sc);
            *(h16x8*)&Bs[row * LDSTR + sc] =
                *(const h16x8*)(Wct + (size_t)(n0 + row) * 1024 + z * 512 + k0 + sc);
        }
        __syncthreads();
#pragma unroll
        for (int s = 0; s < 2; ++s) {
            h16x8 a[4], b[4];
#pragma unroll
            for (int i = 0; i < 4; ++i) {
                a[i] = *(const h16x8*)&As[(wr * 64 + i * 16 + l16) * LDSTR + s * 32 + quad * 8];
                b[i] = *(const h16x8*)&Bs[(wc * 64 + i * 16 + l16) * LDSTR + s * 32 + quad * 8];
            }
#pragma unroll
            for (int ri = 0; ri < 4; ++ri)
#pragma unroll
                for (int ci = 0; ci < 4; ++ci)
                    acc[ri][ci] = __builtin_amdgcn_mfma_f32_16x16x32_f16(
                        a[ri], b[ci], acc[ri][ci], 0, 0, 0);
        }
        __syncthreads();
    }
    half_t* outp = z ? Tws : Hws;
#pragma unroll
    for (int ci = 0; ci < 4; ++ci) {
        int n = n0 + wc * 64 + ci * 16 + l16;
        float bias = z ? 0.0f : bcat[n];
#pragma unroll
        for (int ri = 0; ri < 4; ++ri) {
#pragma unroll
            for (int r = 0; r < 4; ++r) {
                int m = m0 + wr * 64 + ri * 16 + quad * 4 + r;
                outp[(size_t)m * POOL + n] = (half_t)(acc[ri][ci][r] + bias);
            }
        }
    }
}

// ---------------------------------------------------------------------------
// K2b: Wt[n][k] = f16(W_rel[k][n]), n zero-padded to 64. LDS-tiled, 64 blocks.
// ---------------------------------------------------------------------------
__global__ __launch_bounds__(256) void k2b_wt(
    const float* __restrict__ Wrel, half_t* __restrict__ Wt)
{
    __shared__ float Ls[64 * NRC];  // 13056 B
    const int kb = blockIdx.x * 64;
    const int t = threadIdx.x;
    for (int f = t; f < 64 * NRC; f += 256)
        Ls[f] = Wrel[(size_t)kb * NRC + f];
    __syncthreads();
    const int n = t >> 2, kc = t & 3;
    h16x8 o0, o1;
#pragma unroll
    for (int e = 0; e < 8; ++e) {
        o0[e] = (n < NRC) ? (half_t)Ls[(kc * 16 + e) * NRC + n] : (half_t)0.0f;
        o1[e] = (n < NRC) ? (half_t)Ls[(kc * 16 + 8 + e) * NRC + n] : (half_t)0.0f;
    }
    half_t* d = Wt + (size_t)n * POOL + kb + kc * 16;
    *(h16x8*)(d)     = o0;
    *(h16x8*)(d + 8) = o1;
}

// ---------------------------------------------------------------------------
// K3: out[r] = ((H[i_r]+T[j_r]) .* u[r]) @ W_rel + b_rel + freq[bias_idx]
// 64 rows/block, K-split x4, atomicAdd into zeroed out.
// ---------------------------------------------------------------------------
__global__ __launch_bounds__(256) void k3_main(
    const float* __restrict__ unionf,
    const half_t* __restrict__ Hws,
    const half_t* __restrict__ Tws,
    const half_t* __restrict__ Wt,
    const float* __restrict__ brel,
    const float* __restrict__ freq,
    const int* __restrict__ pair_idx,
    const int* __restrict__ obj_preds,
    float* __restrict__ out)
{
    __shared__ __align__(16) half_t As[64 * LDSTR];
    __shared__ __align__(16) half_t Bs[64 * LDSTR];

    const int R0 = blockIdx.x * 64;
    const int kbase = blockIdx.y * (POOL / KSPLIT);
    const int t = threadIdx.x;
    const int wave = t >> 6, lane = t & 63;
    const int quad = lane >> 4, l16 = lane & 15;

    const int ar  = t >> 2;
    const int akb = (t & 3) * 16;

    const int2 pr = *(const int2*)(pair_idx + 2 * (R0 + ar));
    const half_t* Hrow = Hws + (size_t)pr.x * POOL;
    const half_t* Trow = Tws + (size_t)pr.y * POOL;
    const float*  urow = unionf + (size_t)(R0 + ar) * POOL;

    f32x4 acc[4] = {};

    for (int k0 = kbase; k0 < kbase + POOL / KSPLIT; k0 += 64) {
#pragma unroll
        for (int i = 0; i < 2; ++i) {
            h16x8 hv = *(const h16x8*)(Hrow + k0 + akb + 8 * i);
            h16x8 tv = *(const h16x8*)(Trow + k0 + akb + 8 * i);
            float4 ua = *(const float4*)(urow + k0 + akb + 8 * i);
            float4 ub = *(const float4*)(urow + k0 + akb + 8 * i + 4);
            h16x8 o;
            o[0] = (half_t)(((float)hv[0] + (float)tv[0]) * ua.x);
            o[1] = (half_t)(((float)hv[1] + (float)tv[1]) * ua.y);
            o[2] = (half_t)(((float)hv[2] + (float)tv[2]) * ua.z);
            o[3] = (half_t)(((float)hv[3] + (float)tv[3]) * ua.w);
            o[4] = (half_t)(((float)hv[4] + (float)tv[4]) * ub.x);
            o[5] = (half_t)(((float)hv[5] + (float)tv[5]) * ub.y);
            o[6] = (half_t)(((float)hv[6] + (float)tv[6]) * ub.z);
            o[7] = (half_t)(((float)hv[7] + (float)tv[7]) * ub.w);
            *(h16x8*)&As[ar * LDSTR + akb + 8 * i] = o;
        }
        {
            const half_t* src = Wt + (size_t)ar * POOL + k0 + akb;
            *(h16x8*)&Bs[ar * LDSTR + akb]     = *(const h16x8*)(src);
            *(h16x8*)&Bs[ar * LDSTR + akb + 8] = *(const h16x8*)(src + 8);
        }
        __syncthreads();
#pragma unroll
        for (int s = 0; s < 2; ++s) {
            h16x8 a = *(const h16x8*)&As[(wave * 16 + l16) * LDSTR + s * 32 + quad * 8];
#pragma unroll
            for (int nt = 0; nt < 4; ++nt) {
                h16x8 b = *(const h16x8*)&Bs[(nt * 16 + l16) * LDSTR + s * 32 + quad * 8];
                acc[nt] = __builtin_amdgcn_mfma_f32_16x16x32_f16(a, b, acc[nt], 0, 0, 0);
            }
        }
        __syncthreads();
    }
    const bool first = (blockIdx.y == 0);
#pragma unroll
    for (int r = 0; r < 4; ++r) {
        int grow = R0 + wave * 16 + quad * 4 + r;
        const float* frow = nullptr;
        if (first) {
            int2 p = *(const int2*)(pair_idx + 2 * grow);
            frow = freq + (size_t)(obj_preds[p.x] * NOC + obj_preds[p.y]) * NRC;
        }
#pragma unroll
        for (int nt = 0; nt < 4; ++nt) {
            int n = nt * 16 + l16;
            if (n < NRC) {
                float v = acc[nt][r];
                if (first) v += brel[n] + frow[n];
                atomicAdd(&out[(size_t)grow * NRC + n], v);
            }
        }
    }
}

// ---------------------------------------------------------------------------
extern "C" void kernel_launch(void* const* d_in, const int* in_sizes, int n_in,
                              void* d_out, int out_size, void* d_ws, size_t ws_size,
                              hipStream_t stream) {
    const float* edge_ctx  = (const float*)d_in[0];
    const float* unionf    = (const float*)d_in[1];
    const float* We        = (const float*)d_in[2];
    const float* be        = (const float*)d_in[3];
    const float* Wc        = (const float*)d_in[4];
    const float* bcat      = (const float*)d_in[5];
    const float* Wrel      = (const float*)d_in[6];
    const float* brel      = (const float*)d_in[7];
    const float* freq      = (const float*)d_in[8];
    const int*   pair_idx  = (const int*)d_in[9];
    const int*   obj_preds = (const int*)d_in[10];
    float* out = (float*)d_out;

    char* ws = (char*)d_ws;
    half_t* E   = (half_t*)(ws);
    half_t* H   = (half_t*)(ws + 2621440);
    half_t* T   = (half_t*)(ws + 13107200);
    half_t* Wt  = (half_t*)(ws + 23592960);
    half_t* Wct = (half_t*)(ws + 24117248);
    half_t* Wet = (half_t*)(ws + 32505856);

    hipMemsetAsync(out, 0, (size_t)out_size * sizeof(float), stream);

    kt_transpose<<<dim3(HID / 64, 1024 / 64), 256, 0, stream>>>(We, Wet, HID, 1024);
    kt_transpose<<<dim3(1024 / 64, POOL / 64), 256, 0, stream>>>(Wc, Wct, 1024, POOL);
    k2b_wt<<<POOL / 64, 256, 0, stream>>>(Wrel, Wt);
    k1_edge_rep<<<dim3(N_OBJ / 64, 1024 / 64), 256, 0, stream>>>(edge_ctx, Wet, be, E);
    k2_ht<<<dim3(N_OBJ / 128, POOL / 128, 2), 256, 0, stream>>>(E, Wct, bcat, H, T);
    k3_main<<<dim3(N_REL / 64, KSPLIT), 256, 0, stream>>>(unionf, H, T, Wt, brel, freq,
                                                          pair_idx, obj_preds, out);
}

// Round 4
// 462.575 us; speedup vs baseline: 1.1119x; 1.0189x over previous
//
#include <hip/hip_runtime.h>

#define HID 512
#define POOL 4096
#define N_OBJ 1280
#define N_REL 16384
#define NOC 151
#define NRC 51
#define KSPLIT 8

typedef _Float16 half_t;
typedef half_t h16x8 __attribute__((ext_vector_type(8)));
typedef float f32x4 __attribute__((ext_vector_type(4)));

// LDS row stride for 64-k f16 tiles: 72 elems = 144 B. Both b128 reads and
// writes spread uniformly over the 8 four-bank groups (bandwidth-optimal).
#define LDSTR 72

// ---------------------------------------------------------------------------
// device helper: transpose+downconvert one 64x64 tile.
// src: K x N fp32 (n-fast) -> dst: N x K f16 (k-fast)
// ---------------------------------------------------------------------------
__device__ __forceinline__ void kt_tile(
    const float* __restrict__ src, half_t* __restrict__ dst,
    int K, int N, int kb, int nb, half_t* Ts)
{
    const int t = threadIdx.x;
    const int kr = t >> 4;
    const int nc = (t & 15) * 4;
#pragma unroll
    for (int p = 0; p < 4; ++p) {
        float4 v = *(const float4*)(src + (size_t)(kb + kr + 16 * p) * N + nb + nc);
        Ts[(nc + 0) * LDSTR + kr + 16 * p] = (half_t)v.x;
        Ts[(nc + 1) * LDSTR + kr + 16 * p] = (half_t)v.y;
        Ts[(nc + 2) * LDSTR + kr + 16 * p] = (half_t)v.z;
        Ts[(nc + 3) * LDSTR + kr + 16 * p] = (half_t)v.w;
    }
    __syncthreads();
    const int n = t >> 2, kk = (t & 3) * 16;
    half_t* d = dst + (size_t)(nb + n) * K + kb + kk;
    *(h16x8*)(d)     = *(const h16x8*)&Ts[n * LDSTR + kk];
    *(h16x8*)(d + 8) = *(const h16x8*)&Ts[n * LDSTR + kk + 8];
}

// ---------------------------------------------------------------------------
// K_PREP (fused): blocks [0,1024): Wc->Wct ; [1024,1152): We->Wet ;
//                 [1152,1216): Wrel -> Wt (64-col zero-padded transpose)
// ---------------------------------------------------------------------------
__global__ __launch_bounds__(256) void k_prep(
    const float* __restrict__ We, const float* __restrict__ Wc,
    const float* __restrict__ Wrel,
    half_t* __restrict__ Wet, half_t* __restrict__ Wct, half_t* __restrict__ Wt)
{
    __shared__ __align__(16) char smem[64 * NRC * 4];  // 13056 B >= 64*LDSTR*2
    const int b = blockIdx.x;
    if (b < 1024) {
        kt_tile(Wc, Wct, 1024, POOL, (b & 15) * 64, (b >> 4) * 64, (half_t*)smem);
    } else if (b < 1152) {
        const int c = b - 1024;
        kt_tile(We, Wet, HID, 1024, (c & 7) * 64, (c >> 3) * 64, (half_t*)smem);
    } else {
        float* Ls = (float*)smem;
        const int kb = (b - 1152) * 64;
        const int t = threadIdx.x;
        for (int f = t; f < 64 * NRC; f += 256)
            Ls[f] = Wrel[(size_t)kb * NRC + f];
        __syncthreads();
        const int n = t >> 2, kc = t & 3;
        h16x8 o0, o1;
#pragma unroll
        for (int e = 0; e < 8; ++e) {
            o0[e] = (n < NRC) ? (half_t)Ls[(kc * 16 + e) * NRC + n] : (half_t)0.0f;
            o1[e] = (n < NRC) ? (half_t)Ls[(kc * 16 + 8 + e) * NRC + n] : (half_t)0.0f;
        }
        half_t* d = Wt + (size_t)n * POOL + kb + kc * 16;
        *(h16x8*)(d)     = o0;
        *(h16x8*)(d + 8) = o1;
    }
}

// ---------------------------------------------------------------------------
// K1: E(1280x1024) = edge_ctx(1280x512) @ We(512x1024) + be   (f16 out)
// 64x64 tile. B from pre-transposed Wet (1024x512 f16).
// ---------------------------------------------------------------------------
__global__ __launch_bounds__(256) void k1_edge_rep(
    const float* __restrict__ edge_ctx,
    const half_t* __restrict__ Wet,
    const float* __restrict__ be,
    half_t* __restrict__ E)
{
    __shared__ __align__(16) half_t As[64 * LDSTR];
    __shared__ __align__(16) half_t Bs[64 * LDSTR];

    const int m0 = blockIdx.x * 64;
    const int n0 = blockIdx.y * 64;
    const int t = threadIdx.x;
    const int wave = t >> 6, lane = t & 63;
    const int quad = lane >> 4, l16 = lane & 15;

    const int ar  = t >> 2;
    const int akb = (t & 3) * 16;

    f32x4 acc[4] = {};

    for (int k0 = 0; k0 < HID; k0 += 64) {
        {
            const float* src = edge_ctx + (size_t)(m0 + ar) * HID + k0 + akb;
#pragma unroll
            for (int i = 0; i < 2; ++i) {
                float4 va = *(const float4*)(src + 8 * i);
                float4 vb = *(const float4*)(src + 8 * i + 4);
                h16x8 o;
                o[0] = (half_t)va.x; o[1] = (half_t)va.y;
                o[2] = (half_t)va.z; o[3] = (half_t)va.w;
                o[4] = (half_t)vb.x; o[5] = (half_t)vb.y;
                o[6] = (half_t)vb.z; o[7] = (half_t)vb.w;
                *(h16x8*)&As[ar * LDSTR + akb + 8 * i] = o;
            }
        }
        {
            const half_t* src = Wet + (size_t)(n0 + ar) * HID + k0 + akb;
            *(h16x8*)&Bs[ar * LDSTR + akb]     = *(const h16x8*)(src);
            *(h16x8*)&Bs[ar * LDSTR + akb + 8] = *(const h16x8*)(src + 8);
        }
        __syncthreads();
#pragma unroll
        for (int s = 0; s < 2; ++s) {
            h16x8 a = *(const h16x8*)&As[(wave * 16 + l16) * LDSTR + s * 32 + quad * 8];
#pragma unroll
            for (int nt = 0; nt < 4; ++nt) {
                h16x8 b = *(const h16x8*)&Bs[(nt * 16 + l16) * LDSTR + s * 32 + quad * 8];
                acc[nt] = __builtin_amdgcn_mfma_f32_16x16x32_f16(a, b, acc[nt], 0, 0, 0);
            }
        }
        __syncthreads();
    }
#pragma unroll
    for (int nt = 0; nt < 4; ++nt) {
        int n = n0 + nt * 16 + l16;
        float bias = be[n];
#pragma unroll
        for (int r = 0; r < 4; ++r) {
            int m = m0 + wave * 16 + quad * 4 + r;
            E[(size_t)m * 1024 + n] = (half_t)(acc[nt][r] + bias);
        }
    }
}

// ---------------------------------------------------------------------------
// K2: 128x128 tile. z=0: H = E[:,:512]@Wc_top + b_cat ; z=1: T = E[:,512:]@Wc_bot
// ---------------------------------------------------------------------------
__global__ __launch_bounds__(256) void k2_ht(
    const half_t* __restrict__ E,
    const half_t* __restrict__ Wct,
    const float* __restrict__ bcat,
    half_t* __restrict__ Hws,
    half_t* __restrict__ Tws)
{
    __shared__ __align__(16) half_t As[128 * LDSTR];
    __shared__ __align__(16) half_t Bs[128 * LDSTR];

    const int z  = blockIdx.z;
    const int m0 = blockIdx.x * 128;
    const int n0 = blockIdx.y * 128;
    const int t = threadIdx.x;
    const int wave = t >> 6, lane = t & 63;
    const int quad = lane >> 4, l16 = lane & 15;
    const int wr = wave >> 1, wc = wave & 1;

    const int srow = t >> 3;
    const int sc   = (t & 7) * 8;

    f32x4 acc[4][4] = {};

    for (int k0 = 0; k0 < HID; k0 += 64) {
#pragma unroll
        for (int p = 0; p < 4; ++p) {
            int row = srow + 32 * p;
            *(h16x8*)&As[row * LDSTR + sc] =
                *(const h16x8*)(E + (size_t)(m0 + row) * 1024 + z * 512 + k0 + sc);
            *(h16x8*)&Bs[row * LDSTR + sc] =
                *(const h16x8*)(Wct + (size_t)(n0 + row) * 1024 + z * 512 + k0 + sc);
        }
        __syncthreads();
#pragma unroll
        for (int s = 0; s < 2; ++s) {
            h16x8 a[4], b[4];
#pragma unroll
            for (int i = 0; i < 4; ++i) {
                a[i] = *(const h16x8*)&As[(wr * 64 + i * 16 + l16) * LDSTR + s * 32 + quad * 8];
                b[i] = *(const h16x8*)&Bs[(wc * 64 + i * 16 + l16) * LDSTR + s * 32 + quad * 8];
            }
#pragma unroll
            for (int ri = 0; ri < 4; ++ri)
#pragma unroll
                for (int ci = 0; ci < 4; ++ci)
                    acc[ri][ci] = __builtin_amdgcn_mfma_f32_16x16x32_f16(
                        a[ri], b[ci], acc[ri][ci], 0, 0, 0);
        }
        __syncthreads();
    }
    half_t* outp = z ? Tws : Hws;
#pragma unroll
    for (int ci = 0; ci < 4; ++ci) {
        int n = n0 + wc * 64 + ci * 16 + l16;
        float bias = z ? 0.0f : bcat[n];
#pragma unroll
        for (int ri = 0; ri < 4; ++ri) {
#pragma unroll
            for (int r = 0; r < 4; ++r) {
                int m = m0 + wr * 64 + ri * 16 + quad * 4 + r;
                outp[(size_t)m * POOL + n] = (half_t)(acc[ri][ci][r] + bias);
            }
        }
    }
}

// ---------------------------------------------------------------------------
// K3: out[r] = ((H[i_r]+T[j_r]) .* u[r]) @ W_rel + b_rel + freq[bias_idx]
// 64 rows/block, K-split x8 (512 per block), atomicAdd into zeroed out.
// 8 blocks/CU (LDS 18.4KB), 32 waves/CU for latency hiding of the union stream.
// ---------------------------------------------------------------------------
__global__ __launch_bounds__(256) void k3_main(
    const float* __restrict__ unionf,
    const half_t* __restrict__ Hws,
    const half_t* __restrict__ Tws,
    const half_t* __restrict__ Wt,
    const float* __restrict__ brel,
    const float* __restrict__ freq,
    const int* __restrict__ pair_idx,
    const int* __restrict__ obj_preds,
    float* __restrict__ out)
{
    __shared__ __align__(16) half_t As[64 * LDSTR];
    __shared__ __align__(16) half_t Bs[64 * LDSTR];

    const int R0 = blockIdx.x * 64;
    const int kbase = blockIdx.y * (POOL / KSPLIT);
    const int t = threadIdx.x;
    const int wave = t >> 6, lane = t & 63;
    const int quad = lane >> 4, l16 = lane & 15;

    const int ar  = t >> 2;
    const int akb = (t & 3) * 16;

    const int2 pr = *(const int2*)(pair_idx + 2 * (R0 + ar));
    const half_t* Hrow = Hws + (size_t)pr.x * POOL;
    const half_t* Trow = Tws + (size_t)pr.y * POOL;
    const float*  urow = unionf + (size_t)(R0 + ar) * POOL;

    f32x4 acc[4] = {};

    for (int k0 = kbase; k0 < kbase + POOL / KSPLIT; k0 += 64) {
#pragma unroll
        for (int i = 0; i < 2; ++i) {
            h16x8 hv = *(const h16x8*)(Hrow + k0 + akb + 8 * i);
            h16x8 tv = *(const h16x8*)(Trow + k0 + akb + 8 * i);
            float4 ua = *(const float4*)(urow + k0 + akb + 8 * i);
            float4 ub = *(const float4*)(urow + k0 + akb + 8 * i + 4);
            h16x8 o;
            o[0] = (half_t)(((float)hv[0] + (float)tv[0]) * ua.x);
            o[1] = (half_t)(((float)hv[1] + (float)tv[1]) * ua.y);
            o[2] = (half_t)(((float)hv[2] + (float)tv[2]) * ua.z);
            o[3] = (half_t)(((float)hv[3] + (float)tv[3]) * ua.w);
            o[4] = (half_t)(((float)hv[4] + (float)tv[4]) * ub.x);
            o[5] = (half_t)(((float)hv[5] + (float)tv[5]) * ub.y);
            o[6] = (half_t)(((float)hv[6] + (float)tv[6]) * ub.z);
            o[7] = (half_t)(((float)hv[7] + (float)tv[7]) * ub.w);
            *(h16x8*)&As[ar * LDSTR + akb + 8 * i] = o;
        }
        {
            const half_t* src = Wt + (size_t)ar * POOL + k0 + akb;
            *(h16x8*)&Bs[ar * LDSTR + akb]     = *(const h16x8*)(src);
            *(h16x8*)&Bs[ar * LDSTR + akb + 8] = *(const h16x8*)(src + 8);
        }
        __syncthreads();
#pragma unroll
        for (int s = 0; s < 2; ++s) {
            h16x8 a = *(const h16x8*)&As[(wave * 16 + l16) * LDSTR + s * 32 + quad * 8];
#pragma unroll
            for (int nt = 0; nt < 4; ++nt) {
                h16x8 b = *(const h16x8*)&Bs[(nt * 16 + l16) * LDSTR + s * 32 + quad * 8];
                acc[nt] = __builtin_amdgcn_mfma_f32_16x16x32_f16(a, b, acc[nt], 0, 0, 0);
            }
        }
        __syncthreads();
    }
    const bool first = (blockIdx.y == 0);
#pragma unroll
    for (int r = 0; r < 4; ++r) {
        int grow = R0 + wave * 16 + quad * 4 + r;
        const float* frow = nullptr;
        if (first) {
            int2 p = *(const int2*)(pair_idx + 2 * grow);
            frow = freq + (size_t)(obj_preds[p.x] * NOC + obj_preds[p.y]) * NRC;
        }
#pragma unroll
        for (int nt = 0; nt < 4; ++nt) {
            int n = nt * 16 + l16;
            if (n < NRC) {
                float v = acc[nt][r];
                if (first) v += brel[n] + frow[n];
                atomicAdd(&out[(size_t)grow * NRC + n], v);
            }
        }
    }
}

// ---------------------------------------------------------------------------
extern "C" void kernel_launch(void* const* d_in, const int* in_sizes, int n_in,
                              void* d_out, int out_size, void* d_ws, size_t ws_size,
                              hipStream_t stream) {
    const float* edge_ctx  = (const float*)d_in[0];
    const float* unionf    = (const float*)d_in[1];
    const float* We        = (const float*)d_in[2];
    const float* be        = (const float*)d_in[3];
    const float* Wc        = (const float*)d_in[4];
    const float* bcat      = (const float*)d_in[5];
    const float* Wrel      = (const float*)d_in[6];
    const float* brel      = (const float*)d_in[7];
    const float* freq      = (const float*)d_in[8];
    const int*   pair_idx  = (const int*)d_in[9];
    const int*   obj_preds = (const int*)d_in[10];
    float* out = (float*)d_out;

    char* ws = (char*)d_ws;
    half_t* E   = (half_t*)(ws);
    half_t* H   = (half_t*)(ws + 2621440);
    half_t* T   = (half_t*)(ws + 13107200);
    half_t* Wt  = (half_t*)(ws + 23592960);
    half_t* Wct = (half_t*)(ws + 24117248);
    half_t* Wet = (half_t*)(ws + 32505856);

    hipMemsetAsync(out, 0, (size_t)out_size * sizeof(float), stream);

    k_prep<<<1216, 256, 0, stream>>>(We, Wc, Wrel, Wet, Wct, Wt);
    k1_edge_rep<<<dim3(N_OBJ / 64, 1024 / 64), 256, 0, stream>>>(edge_ctx, Wet, be, E);
    k2_ht<<<dim3(N_OBJ / 128, POOL / 128, 2), 256, 0, stream>>>(E, Wct, bcat, H, T);
    k3_main<<<dim3(N_REL / 64, KSPLIT), 256, 0, stream>>>(unionf, H, T, Wt, brel, freq,
                                                          pair_idx, obj_preds, out);
}